// Round 7
// baseline (164.647 us; speedup 1.0000x reference)
//
#include <hip/hip_runtime.h>
#include <math.h>

#define BB   128
#define SS   2048
#define DIN  1024
#define DSRC 1024
#define DOUT 1024
#define WW   64
#define WLEN 129
#define HH   512
#define WCH  17     // w-chunk per score block; 8 chunks cover 136 >= 129

// workspace layout (bytes)
#define OFF_WSI   0
#define OFF_P     512
#define OFF_LEN   1024
#define OFF_PD    4096        // double[128][32] = 32 KB (per-b, per-fc1-block tanh*W2 partials)
#define OFF_X32   36864       // float[128][1024] = 512 KB
#define OFF_OPI   561152      // float[128][1024] = 512 KB (input-half of out GEMM, final)
#define OFF_C32   1085440     // float[128][1024] = 512 KB
#define OFF_CPART 1609728     // float[128][8][1024] = 4 MB
#define OFF_MPART 5804032
#define OFF_LPART 5808128
#define OFF_SPART 5812224     // float[128][8][17]
#define WS_NEED   5881856

// d_out layout (floats)
#define DO_A    (BB*DOUT)        // 131072
#define DO_WS   (DO_A + BB*WLEN) // 147584
#define DO_WE   (DO_WS + BB)     // 147712

// ---------------- full-K (K=1024) GEMM core ----------------
// 512 thr = 8 waves x 2 cols (16 cols/block), lanes hold 2 rows (float2 from LDS).
// A [128][lda] f32 staged in 16 chunks of [128][64] with register prefetch.
// f64 accumulation of 16-K f32 chunks, ascending k — same chunk values as the R3 split GEMMs.
__device__ __forceinline__ void gemmfk(
    const int t, const float* __restrict__ A, const int lda,
    const float* __restrict__ wbase, const int ldw,     // wbase = row j0 of W
    float* __restrict__ alds /* [64][130] */, double (&dac)[2][2])
{
    const int lane = t & 63;
    float4 pf[4];
    #pragma unroll
    for (int q = 0; q < 4; ++q) {
        const int f4 = t + 512*q;
        const int bb = f4 >> 4, c4 = f4 & 15;
        pf[q] = *reinterpret_cast<const float4*>(A + (size_t)bb*lda + c4*4);
    }
    for (int c = 0; c < 16; ++c) {
        __syncthreads();
        #pragma unroll
        for (int q = 0; q < 4; ++q) {
            const int f4 = t + 512*q;
            const int bb = f4 >> 4, c4 = f4 & 15;
            alds[(c4*4+0)*130 + bb] = pf[q].x;
            alds[(c4*4+1)*130 + bb] = pf[q].y;
            alds[(c4*4+2)*130 + bb] = pf[q].z;
            alds[(c4*4+3)*130 + bb] = pf[q].w;
        }
        __syncthreads();
        if (c + 1 < 16) {
            #pragma unroll
            for (int q = 0; q < 4; ++q) {
                const int f4 = t + 512*q;
                const int bb = f4 >> 4, c4 = f4 & 15;
                pf[q] = *reinterpret_cast<const float4*>(A + (size_t)bb*lda + (c+1)*64 + c4*4);
            }
        }
        const float* wr = wbase + c*64;
        #pragma unroll
        for (int kk16 = 0; kk16 < 64; kk16 += 16) {
            float fa[2][2];
            fa[0][0] = 0.f; fa[0][1] = 0.f; fa[1][0] = 0.f; fa[1][1] = 0.f;
            #pragma unroll
            for (int kk = 0; kk < 16; ++kk) {
                const int k = kk16 + kk;
                const float2 av = *reinterpret_cast<const float2*>(&alds[k*130 + 2*lane]);
                #pragma unroll
                for (int jj = 0; jj < 2; ++jj) {
                    const float wvv = wr[jj*ldw + k];
                    fa[jj][0] = fmaf(wvv, av.x, fa[jj][0]);
                    fa[jj][1] = fmaf(wvv, av.y, fa[jj][1]);
                }
            }
            dac[0][0] += (double)fa[0][0]; dac[0][1] += (double)fa[0][1];
            dac[1][0] += (double)fa[1][0]; dac[1][1] += (double)fa[1][1];
        }
    }
}

// ---------------- L1: combo = gemm1 full-K (64) | gemm2-input-half full-K (64) | lengths (128) ----
__global__ __launch_bounds__(512)
void k_combo(const float* __restrict__ input, const float* __restrict__ Wi,
             const float* __restrict__ Wo, const unsigned char* __restrict__ mask,
             float* __restrict__ x32, float* __restrict__ opi, int* __restrict__ lengths)
{
    __shared__ __align__(16) float alds[64*130];
    const int blk = blockIdx.x, t = threadIdx.x;
    const int lane = t & 63;
    const int wvid = __builtin_amdgcn_readfirstlane(t >> 6);

    if (blk < 64) {
        // x32 = input @ Wi^T  (final f32, no partials)
        double dac[2][2];
        dac[0][0] = 0.0; dac[0][1] = 0.0; dac[1][0] = 0.0; dac[1][1] = 0.0;
        const int j0 = blk*16 + wvid*2;
        gemmfk(t, input, DIN, Wi + (size_t)j0*DIN, DIN, alds, dac);
        #pragma unroll
        for (int i = 0; i < 2; ++i) {
            const int b = 2*lane + i;
            x32[(size_t)b*DSRC + j0 + 0] = (float)dac[0][i];
            x32[(size_t)b*DSRC + j0 + 1] = (float)dac[1][i];
        }
    } else if (blk < 128) {
        // opi = input @ Wo[:,1024:]^T  (final f32)
        double dac[2][2];
        dac[0][0] = 0.0; dac[0][1] = 0.0; dac[1][0] = 0.0; dac[1][1] = 0.0;
        const int j0 = (blk - 64)*16 + wvid*2;
        gemmfk(t, input, DIN, Wo + (size_t)j0*(DIN+DSRC) + 1024, DIN + DSRC, alds, dac);
        #pragma unroll
        for (int i = 0; i < 2; ++i) {
            const int b = 2*lane + i;
            opi[(size_t)b*DOUT + j0 + 0] = (float)dac[0][i];
            opi[(size_t)b*DOUT + j0 + 1] = (float)dac[1][i];
        }
    } else {
        const int b = blk - 128;
        const bool is_u8 = (mask[(size_t)SS*BB - 1] != 0);
        int cnt = 0;
        if (is_u8) {
            #pragma unroll
            for (int q = 0; q < 4; ++q)
                cnt += (mask[(size_t)(t + 512*q)*BB + b] != 0) ? 1 : 0;
        } else {
            const int* m32 = (const int*)mask;
            #pragma unroll
            for (int q = 0; q < 4; ++q)
                cnt += (m32[(size_t)(t + 512*q)*BB + b] != 0) ? 1 : 0;
        }
        int* red = (int*)alds;
        red[t] = cnt;
        __syncthreads();
        for (int st = 256; st >= 1; st >>= 1) {
            if (t < st) red[t] += red[t + st];
            __syncthreads();
        }
        if (t == 0) lengths[b] = SS - red[0];
    }
}

// ---------------- L2: fc1 full-K (32 blocks) + per-block tanh*W2 partials -> pd ----------------
// Each block owns 16 complete z1 columns -> can apply tanh and the W2 dot for those columns.
__global__ __launch_bounds__(512)
void k_fc1(const float* __restrict__ x32, const float* __restrict__ W1,
           const float* __restrict__ b1, const float* __restrict__ W2f,
           double* __restrict__ pd)
{
    __shared__ __align__(16) float alds[64*130];
    const int blk = blockIdx.x, t = threadIdx.x;
    const int lane = t & 63;
    const int wvid = __builtin_amdgcn_readfirstlane(t >> 6);
    const int j0 = blk*16 + wvid*2;

    double dac[2][2];
    dac[0][0] = 0.0; dac[0][1] = 0.0; dac[1][0] = 0.0; dac[1][1] = 0.0;
    gemmfk(t, x32, DSRC, W1 + (size_t)j0*DIN, DIN, alds, dac);

    // tail: v_i = sum over this thread's 2 cols of tanh(z1 + b1) * W2
    double v[2];
    #pragma unroll
    for (int i = 0; i < 2; ++i) {
        v[i] = 0.0;
        #pragma unroll
        for (int jj = 0; jj < 2; ++jj) {
            const int j = j0 + jj;
            v[i] += tanh(dac[jj][i] + (double)b1[j]) * (double)W2f[j];
        }
    }
    __syncthreads();                       // alds reuse
    double* pds = (double*)alds;           // [128][8]
    #pragma unroll
    for (int i = 0; i < 2; ++i) pds[(2*lane + i)*8 + wvid] = v[i];
    __syncthreads();
    if (t < 128) {
        double s = 0.0;
        #pragma unroll
        for (int w = 0; w < 8; ++w) s += pds[t*8 + w];   // fixed wave order: deterministic
        pd[(size_t)t*32 + blk] = s;
    }
}

// ---------------- L3: score with micro fc2-prologue (pd reduce + sigmoid; no tanh/libm loop) -----
// grid (8, 128), 256 threads. All 8 wc-blocks of a b compute identical W0/p (fixed butterfly).
__global__ __launch_bounds__(256)
void k_score(const float* __restrict__ x32, const float* __restrict__ src,
             const double* __restrict__ pd, const float* __restrict__ b2,
             const int* __restrict__ lengths,
             int* __restrict__ wsi, float* __restrict__ pbuf,
             float* __restrict__ cpart, float* __restrict__ mpart,
             float* __restrict__ lpart, float* __restrict__ spart,
             float* __restrict__ out)
{
    const int wc = blockIdx.x, b = blockIdx.y;
    const int t = threadIdx.x, lane = t & 63, wv = t >> 6;

    __shared__ float red[WCH][4];
    __shared__ float s_sh[WCH];
    __shared__ int   W0sh;
    __shared__ float psh;

    const int L = lengths[b];

    // ---- fc2 tail: reduce 32 pd partials (wave 0), sigmoid, W0/p ----
    {
        double v = 0.0;
        if (t < 32) v = pd[(size_t)b*32 + t];
        if (t < 64) {
            #pragma unroll
            for (int off = 1; off <= 16; off <<= 1) v += __shfl_xor(v, off);
        }
        if (t == 0) {
            const double z2  = v + (double)b2[0];
            const double sig = 1.0 / (1.0 + exp(-z2));
            const double wsf = (double)L * sig;        // p - W
            int W0 = (int)rint(wsf);
            if (W0 < 0) W0 = 0;
            if (W0 > SS - WLEN) W0 = SS - WLEN;
            W0sh = W0;
            psh  = (float)(wsf + 64.0);
            if (wc == 0) {
                wsi[b]  = W0;
                pbuf[b] = (float)(wsf + 64.0);
                out[DO_WS + b] = (float)W0;
                out[DO_WE + b] = (float)(W0 + WLEN);
            }
        }
        __syncthreads();
    }
    const int   w0 = W0sh;
    const float p  = psh;

    // ---- score body (R3-proven) ----
    const float4 x4 = *reinterpret_cast<const float4*>(x32 + b*DSRC + 4*t);

    float4 sel[WCH];
    #pragma unroll
    for (int i = 0; i < WCH; ++i) {
        const int w = wc*WCH + i;
        if (w < WLEN) {
            const size_t off = ((size_t)(w0 + w) * BB + b) * DSRC + 4*t;
            sel[i] = *reinterpret_cast<const float4*>(src + off);
        } else sel[i] = make_float4(0.f, 0.f, 0.f, 0.f);
    }

    float w_[32];
    #pragma unroll
    for (int i = 0; i < WCH; ++i)
        w_[i] = fmaf(x4.x, sel[i].x, fmaf(x4.y, sel[i].y, fmaf(x4.z, sel[i].z, x4.w * sel[i].w)));
    #pragma unroll
    for (int i = WCH; i < 32; ++i) w_[i] = 0.f;

    #pragma unroll
    for (int k = 0; k < 5; ++k) {
        const int dist = 1 << k;
        const bool hi = (lane >> k) & 1;
        const int n2 = 32 >> (k + 1);
        #pragma unroll
        for (int i = 0; i < n2; ++i) {
            const float keep = hi ? w_[2*i+1] : w_[2*i];
            const float send = hi ? w_[2*i]   : w_[2*i+1];
            w_[i] = keep + __shfl_xor(send, dist);
        }
    }
    const float tot = w_[0] + __shfl_xor(w_[0], 32);

    if (lane < WCH) red[lane][wv] = tot;
    __syncthreads();
    if (t < WCH) {
        const int w = wc*WCH + t;
        float s;
        if (w < WLEN) {
            const float sum = red[t][0] + red[t][1] + red[t][2] + red[t][3];
            const int pos = w0 + w;
            s = (pos >= WW && pos < L + WW) ? sum : 1e-14f;
        } else s = -INFINITY;
        s_sh[t] = s;
    }
    __syncthreads();

    float sv[WCH];
    #pragma unroll
    for (int i = 0; i < WCH; ++i) sv[i] = s_sh[i];
    float m_loc = -INFINITY;
    #pragma unroll
    for (int i = 0; i < WCH; ++i) m_loc = fmaxf(m_loc, sv[i]);
    float l_loc = 0.f;
    float4 c = make_float4(0.f, 0.f, 0.f, 0.f);
    #pragma unroll
    for (int i = 0; i < WCH; ++i) {
        const float e = expf(sv[i] - m_loc);       // -inf -> 0 for w >= WLEN
        l_loc += e;
        const int w = wc*WCH + i;
        const float d = (float)(w0 + w) - p;
        const float g = expf(d*d * (-1.0f/2048.0f));
        const float wt = e * g;
        c.x = fmaf(wt, sel[i].x, c.x);
        c.y = fmaf(wt, sel[i].y, c.y);
        c.z = fmaf(wt, sel[i].z, c.z);
        c.w = fmaf(wt, sel[i].w, c.w);
    }
    *reinterpret_cast<float4*>(cpart + ((size_t)(b*8 + wc))*DSRC + 4*t) = c;
    if (t == 0) { mpart[b*8 + wc] = m_loc; lpart[b*8 + wc] = l_loc; }
    if (t < WCH) spart[(b*8 + wc)*WCH + t] = s_sh[t];
}

// ---------------- L4: merge 8 partials per b -> c32 + a output (R3 verbatim) ----------------
__global__ __launch_bounds__(256)
void k_merge(const float* __restrict__ cpart, const float* __restrict__ mpart,
             const float* __restrict__ lpart, const float* __restrict__ spart,
             const int* __restrict__ wsi, const float* __restrict__ pbuf,
             float* __restrict__ c32, float* __restrict__ dout)
{
    const int b = blockIdx.x, t = threadIdx.x;
    __shared__ float mv[8], lv[8];
    if (t < 8) { mv[t] = mpart[b*8 + t]; lv[t] = lpart[b*8 + t]; }
    __syncthreads();
    float m = -INFINITY;
    #pragma unroll
    for (int i = 0; i < 8; ++i) m = fmaxf(m, mv[i]);
    float l = 0.f;
    float fac[8];
    #pragma unroll
    for (int i = 0; i < 8; ++i) { fac[i] = expf(mv[i] - m); l = fmaf(lv[i], fac[i], l); }
    const float inv = 1.0f / l;

    float4 c = make_float4(0.f, 0.f, 0.f, 0.f);
    #pragma unroll
    for (int i = 0; i < 8; ++i) {
        const float4 cp = *reinterpret_cast<const float4*>(cpart + ((size_t)(b*8 + i))*DSRC + 4*t);
        c.x = fmaf(cp.x, fac[i], c.x);
        c.y = fmaf(cp.y, fac[i], c.y);
        c.z = fmaf(cp.z, fac[i], c.z);
        c.w = fmaf(cp.w, fac[i], c.w);
    }
    c.x *= inv; c.y *= inv; c.z *= inv; c.w *= inv;
    *reinterpret_cast<float4*>(c32 + (size_t)b*DSRC + 4*t) = c;

    if (t < WLEN) {
        const int wc = t / WCH, i = t % WCH;
        const float s = spart[(b*8 + wc)*WCH + i];
        const float d = (float)(wsi[b] + t) - pbuf[b];
        const float g = expf(d*d * (-1.0f/2048.0f));
        dout[DO_A + b*WLEN + t] = expf(s - m) * inv * g;
    }
}

// ---------------- L5: out = tanh(c32 @ Wo_c^T + opi)  (full-K, final) ----------------
__global__ __launch_bounds__(512)
void k_gemm2cf(const float* __restrict__ c32, const float* __restrict__ Wo,
               const float* __restrict__ opi, float* __restrict__ out)
{
    __shared__ __align__(16) float alds[64*130];
    const int blk = blockIdx.x, t = threadIdx.x;
    const int lane = t & 63;
    const int wvid = __builtin_amdgcn_readfirstlane(t >> 6);
    const int j0 = blk*16 + wvid*2;

    double dac[2][2];
    dac[0][0] = 0.0; dac[0][1] = 0.0; dac[1][0] = 0.0; dac[1][1] = 0.0;
    gemmfk(t, c32, DSRC, Wo + (size_t)j0*(DIN+DSRC), DIN + DSRC, alds, dac);

    #pragma unroll
    for (int i = 0; i < 2; ++i) {
        const int b = 2*lane + i;
        #pragma unroll
        for (int jj = 0; jj < 2; ++jj) {
            const int j = j0 + jj;
            out[(size_t)b*DOUT + j] = tanhf((float)dac[jj][i] + opi[(size_t)b*DOUT + j]);
        }
    }
}

extern "C" void kernel_launch(void* const* d_in, const int* in_sizes, int n_in,
                              void* d_out, int out_size, void* d_ws, size_t ws_size,
                              hipStream_t stream)
{
    const float* input = (const float*)d_in[0];
    const float* src   = (const float*)d_in[1];
    const unsigned char* mask = (const unsigned char*)d_in[2];
    const float* Wi = (const float*)d_in[3];
    const float* Wo = (const float*)d_in[4];
    const float* W1 = (const float*)d_in[5];
    const float* b1 = (const float*)d_in[6];
    const float* W2 = (const float*)d_in[7];
    const float* b2 = (const float*)d_in[8];
    float* out = (float*)d_out;

    if (ws_size < (size_t)WS_NEED) return;

    char* ws = (char*)d_ws;
    int*    wsi     = (int*)   (ws + OFF_WSI);
    float*  pbuf    = (float*) (ws + OFF_P);
    int*    lengths = (int*)   (ws + OFF_LEN);
    double* pd      = (double*)(ws + OFF_PD);
    float*  x32     = (float*) (ws + OFF_X32);
    float*  opi     = (float*) (ws + OFF_OPI);
    float*  c32     = (float*) (ws + OFF_C32);
    float*  cpart   = (float*) (ws + OFF_CPART);
    float*  mpart   = (float*) (ws + OFF_MPART);
    float*  lpart   = (float*) (ws + OFF_LPART);
    float*  spart   = (float*) (ws + OFF_SPART);

    // L1: x32 = in@Wi^T (full-K) || opi = in@Wo_i^T (full-K) || lengths
    k_combo<<<256, 512, 0, stream>>>(input, Wi, Wo, mask, x32, opi, lengths);
    // L2: fc1 full-K + per-block tanh*W2 partials -> pd[128][32]
    k_fc1<<<32, 512, 0, stream>>>(x32, W1, b1, W2, pd);
    // L3: score (micro fc2-prologue: pd reduce + sigmoid -> W0/p)
    k_score<<<dim3(8,128), 256, 0, stream>>>(x32, src, pd, b2, lengths,
                                             wsi, pbuf, cpart, mpart, lpart, spart, out);
    // L4: merge partials -> c32 + a
    k_merge<<<128, 256, 0, stream>>>(cpart, mpart, lpart, spart, wsi, pbuf, c32, out);
    // L5: out = tanh(c32@Wo_c^T + opi)  (full-K, final)
    k_gemm2cf<<<64, 512, 0, stream>>>(c32, Wo, opi, out);
}

// Round 8
// 88.424 us; speedup vs baseline: 1.8620x; 1.8620x over previous
//
#include <hip/hip_runtime.h>
#include <math.h>

#define BB   128
#define SS   2048
#define DIN  1024
#define DSRC 1024
#define DOUT 1024
#define WW   64
#define WLEN 129
#define HH   512
#define WCH  17     // w-chunk per score block; 8 chunks cover 136 >= 129
#define GW   136    // gaussian table width (WLEN padded)

// workspace layout (bytes) — R3 layout, c32 slot retired
#define OFF_WSI   0
#define OFF_P     512
#define OFF_LEN   1024
#define OFF_GTAB  4096        // float[128][136]
#define OFF_XP    73728       // double[4][128][1024] = 4 MB
#define OFF_X32   4268032     // float[128][1024]
#define OFF_Z1P   4792320     // double[4][128][512] = 2 MB
#define OFF_CPART 7413760     // float[128][8][1024] = 4 MB
#define OFF_MPART 11608064
#define OFF_LPART 11612160
#define OFF_SPART 11616256    // float[128][8][17]
#define OFF_OP    11685888    // float[8][128][1024] = 4 MB ([0..3]=c-half, [4..7]=input-half)
#define WS_NEED   15880192

// d_out layout (floats)
#define DO_A    (BB*DOUT)        // 131072
#define DO_WS   (DO_A + BB*WLEN) // 147584
#define DO_WE   (DO_WS + BB)     // 147712

// ---------------- 16-col tiled GEMM stage (f32 products, f64 chunk accumulation) ----------------
// R3-proven geometry: NJB = NTOT/16 j-blocks, 4 splits, 8 waves x 2 cols, lanes hold 2 b rows.
template<int NTOT, int KRANGE, bool F64OUT>
__device__ __forceinline__ void gemm16(const int gblk, const int t,
    const float* __restrict__ A, const int lda,
    const float* __restrict__ Wt, const int ldw,
    void* __restrict__ outp, float* __restrict__ alds /* [64][130] */)
{
    constexpr int NJB = NTOT / 16;
    const int jb = gblk % NJB;
    const int ks = gblk / NJB;
    const int lane = t & 63;
    const int wvid = __builtin_amdgcn_readfirstlane(t >> 6);
    const int j0 = jb * 16 + wvid * 2;
    const int k0 = ks * KRANGE;

    double dac[2][2];
    dac[0][0] = 0.0; dac[0][1] = 0.0; dac[1][0] = 0.0; dac[1][1] = 0.0;

    const float* wbase = Wt + (size_t)j0 * ldw;

    for (int kc = 0; kc < KRANGE; kc += 64) {
        const int kg = k0 + kc;
        __syncthreads();
        #pragma unroll
        for (int q = 0; q < 4; ++q) {
            const int f4 = t + 512 * q;
            const int bb = f4 >> 4, c4 = f4 & 15;
            const float4 v = *reinterpret_cast<const float4*>(A + (size_t)bb * lda + kg + c4 * 4);
            alds[(c4*4+0)*130 + bb] = v.x;
            alds[(c4*4+1)*130 + bb] = v.y;
            alds[(c4*4+2)*130 + bb] = v.z;
            alds[(c4*4+3)*130 + bb] = v.w;
        }
        __syncthreads();
        const float* wr = wbase + kg;
        #pragma unroll
        for (int kk16 = 0; kk16 < 64; kk16 += 16) {
            float fa[2][2];
            fa[0][0] = 0.f; fa[0][1] = 0.f; fa[1][0] = 0.f; fa[1][1] = 0.f;
            #pragma unroll
            for (int kk = 0; kk < 16; ++kk) {
                const int k = kk16 + kk;
                const float2 av = *reinterpret_cast<const float2*>(&alds[k*130 + 2*lane]);
                #pragma unroll
                for (int jj = 0; jj < 2; ++jj) {
                    const float wvv = wr[jj*ldw + k];
                    fa[jj][0] = fmaf(wvv, av.x, fa[jj][0]);
                    fa[jj][1] = fmaf(wvv, av.y, fa[jj][1]);
                }
            }
            #pragma unroll
            for (int jj = 0; jj < 2; ++jj) {
                dac[jj][0] += (double)fa[jj][0];
                dac[jj][1] += (double)fa[jj][1];
            }
        }
    }
    #pragma unroll
    for (int i = 0; i < 2; ++i) {
        const int b = 2*lane + i;
        const size_t base = ((size_t)ks * BB + b) * NTOT + j0;
        if constexpr (F64OUT) {
            double* o = (double*)outp;
            o[base + 0] = dac[0][i];
            o[base + 1] = dac[1][i];
        } else {
            float* o = (float*)outp;
            o[base + 0] = (float)dac[0][i];
            o[base + 1] = (float)dac[1][i];
        }
    }
}

// ---------------- L1: combo = gemm1 (256) | gemm2-input-half (256) | lengths (128) ----------------
__global__ __launch_bounds__(512)
void k_combo(const float* __restrict__ input, const float* __restrict__ Wi,
             const float* __restrict__ Wo, const unsigned char* __restrict__ mask,
             double* __restrict__ xp, float* __restrict__ op4, int* __restrict__ lengths)
{
    __shared__ __align__(16) float alds[64*130];
    const int blk = blockIdx.x, t = threadIdx.x;
    if (blk < 256) {
        // x partials = input @ Wi^T  (f64 partials, 4 splits)
        gemm16<1024, 256, true>(blk, t, input, DIN, Wi, DIN, xp, alds);
    } else if (blk < 512) {
        // op[4..7] = input @ Wo[:,1024:]^T  (independent of everything downstream)
        gemm16<1024, 256, false>(blk - 256, t, input, DIN, Wo + 1024, DIN + DSRC, op4, alds);
    } else {
        const int b = blk - 512;
        const bool is_u8 = (mask[(size_t)SS*BB - 1] != 0);
        int cnt = 0;
        if (is_u8) {
            #pragma unroll
            for (int q = 0; q < 4; ++q)
                cnt += (mask[(size_t)(t + 512*q)*BB + b] != 0) ? 1 : 0;
        } else {
            const int* m32 = (const int*)mask;
            #pragma unroll
            for (int q = 0; q < 4; ++q)
                cnt += (m32[(size_t)(t + 512*q)*BB + b] != 0) ? 1 : 0;
        }
        int* red = (int*)alds;
        red[t] = cnt;
        __syncthreads();
        for (int st = 256; st >= 1; st >>= 1) {
            if (t < st) red[t] += red[t + st];
            __syncthreads();
        }
        if (t == 0) lengths[b] = SS - red[0];
    }
}

// ---------------- L2: reduce xp (4 f64 partials) -> x32 ----------------
__global__ __launch_bounds__(512)
void k_xred(const double* __restrict__ xp, float* __restrict__ x32)
{
    const int i = blockIdx.x * 512 + threadIdx.x;
    double s = 0.0;
    #pragma unroll
    for (int ks = 0; ks < 4; ++ks) s += xp[(size_t)ks * (BB*DSRC) + i];
    x32[i] = (float)s;
}

// ---------------- L3: fc1 partials = x32 @ W1^T ----------------
__global__ __launch_bounds__(512)
void k_fc1(const float* __restrict__ x32, const float* __restrict__ W1, double* __restrict__ z1p)
{
    __shared__ __align__(16) float alds[64*130];
    gemm16<512, 256, true>(blockIdx.x, threadIdx.x, x32, DSRC, W1, DIN, z1p, alds);
}

// ---------------- L4: fc2: z1 reduce + tanh + dot(W2) + sigmoid -> W0, p, gtab, ws/we ------------
__global__ __launch_bounds__(64)
void k_fc2(const double* __restrict__ z1p, const float* __restrict__ b1,
           const float* __restrict__ W2f, const float* __restrict__ b2,
           const int* __restrict__ lengths, int* __restrict__ wsi,
           float* __restrict__ pbuf, float* __restrict__ gtab, float* __restrict__ dout)
{
    const int b = blockIdx.x, lane = threadIdx.x;
    double part = 0.0;
    #pragma unroll
    for (int q = 0; q < 8; ++q) {
        const int h = lane + 64*q;
        double z = 0.0;
        #pragma unroll
        for (int ks = 0; ks < 4; ++ks) z += z1p[((size_t)ks*BB + b)*HH + h];
        z += (double)b1[h];
        part += tanh(z) * (double)W2f[h];
    }
    #pragma unroll
    for (int off = 32; off >= 1; off >>= 1) part += __shfl_xor(part, off);
    // all lanes now hold the full sum -> replicate the (deterministic) f64 tail
    const double z2  = part + (double)b2[0];
    const double sig = 1.0 / (1.0 + exp(-z2));
    const double wsf = (double)lengths[b] * sig;   // p - W
    int W0 = (int)rint(wsf);
    if (W0 < 0) W0 = 0;
    if (W0 > SS - WLEN) W0 = SS - WLEN;
    const float pf = (float)(wsf + 64.0);
    if (lane == 0) {
        wsi[b]  = W0;
        pbuf[b] = pf;
        dout[DO_WS + b] = (float)W0;
        dout[DO_WE + b] = (float)(W0 + WLEN);
    }
    #pragma unroll
    for (int q = 0; q < 3; ++q) {
        const int w = lane + 64*q;
        if (w < GW) {
            float g = 0.f;
            if (w < WLEN) {
                const float d = (float)(W0 + w) - pf;
                g = expf(d*d * (-1.0f/2048.0f));
            }
            gtab[b*GW + w] = g;
        }
    }
}

// ---------------- L5: per-(b, w-chunk) scores + local softmax + partial c (R3 verbatim) ----------
__global__ __launch_bounds__(256)
void k_score(const float* __restrict__ x32, const float* __restrict__ src,
             const int* __restrict__ wsi, const float* __restrict__ pbuf,
             const int* __restrict__ lengths, const float* __restrict__ gtab,
             float* __restrict__ cpart, float* __restrict__ mpart,
             float* __restrict__ lpart, float* __restrict__ spart)
{
    const int wc = blockIdx.x, b = blockIdx.y;
    const int t = threadIdx.x, lane = t & 63, wv = t >> 6;
    const int   w0 = wsi[b];
    const int   L  = lengths[b];

    const float4 x4 = *reinterpret_cast<const float4*>(x32 + b*DSRC + 4*t);

    float4 sel[WCH];
    #pragma unroll
    for (int i = 0; i < WCH; ++i) {
        const int w = wc*WCH + i;
        if (w < WLEN) {
            const size_t off = ((size_t)(w0 + w) * BB + b) * DSRC + 4*t;
            sel[i] = *reinterpret_cast<const float4*>(src + off);
        } else sel[i] = make_float4(0.f, 0.f, 0.f, 0.f);
    }

    float w_[32];
    #pragma unroll
    for (int i = 0; i < WCH; ++i)
        w_[i] = fmaf(x4.x, sel[i].x, fmaf(x4.y, sel[i].y, fmaf(x4.z, sel[i].z, x4.w * sel[i].w)));
    #pragma unroll
    for (int i = WCH; i < 32; ++i) w_[i] = 0.f;

    // multi-value butterfly: after 5 levels lane holds value (lane&31) summed over its 32-lane half
    #pragma unroll
    for (int k = 0; k < 5; ++k) {
        const int dist = 1 << k;
        const bool hi = (lane >> k) & 1;
        const int n2 = 32 >> (k + 1);
        #pragma unroll
        for (int i = 0; i < n2; ++i) {
            const float keep = hi ? w_[2*i+1] : w_[2*i];
            const float send = hi ? w_[2*i]   : w_[2*i+1];
            w_[i] = keep + __shfl_xor(send, dist);
        }
    }
    const float tot = w_[0] + __shfl_xor(w_[0], 32);   // full 64-lane sum of row (lane&31)

    __shared__ float red[WCH][4];
    __shared__ float s_sh[WCH];
    if (lane < WCH) red[lane][wv] = tot;
    __syncthreads();
    if (t < WCH) {
        const int w = wc*WCH + t;
        float s;
        if (w < WLEN) {
            const float sum = red[t][0] + red[t][1] + red[t][2] + red[t][3];
            const int pos = w0 + w;
            s = (pos >= WW && pos < L + WW) ? sum : 1e-14f;
        } else s = -INFINITY;
        s_sh[t] = s;
    }
    __syncthreads();

    float sv[WCH];
    #pragma unroll
    for (int i = 0; i < WCH; ++i) sv[i] = s_sh[i];
    float m_loc = -INFINITY;
    #pragma unroll
    for (int i = 0; i < WCH; ++i) m_loc = fmaxf(m_loc, sv[i]);
    float l_loc = 0.f;
    float4 c = make_float4(0.f, 0.f, 0.f, 0.f);
    #pragma unroll
    for (int i = 0; i < WCH; ++i) {
        const float e = expf(sv[i] - m_loc);       // -inf -> 0 for w >= WLEN
        l_loc += e;
        const float g = gtab[b*GW + wc*WCH + i];   // 0 beyond WLEN
        const float wt = e * g;
        c.x = fmaf(wt, sel[i].x, c.x);
        c.y = fmaf(wt, sel[i].y, c.y);
        c.z = fmaf(wt, sel[i].z, c.z);
        c.w = fmaf(wt, sel[i].w, c.w);
    }
    *reinterpret_cast<float4*>(cpart + ((size_t)(b*8 + wc))*DSRC + 4*t) = c;
    if (t == 0) { mpart[b*8 + wc] = m_loc; lpart[b*8 + wc] = l_loc; }
    if (t < WCH) spart[(b*8 + wc)*WCH + t] = s_sh[t];
}

// ---------------- L6: gemm2c with merge folded into A-staging (R2-verified pattern) ----------------
// 256 blocks (64 jb x 4 ks), 512 thr. A[b][k] = (sum_i cpart[b][i][k]*fac[i]) * inv — bit-exact
// replica of k_merge's math; cpart re-read 8x per staged chunk (L2-resident, ~64 MB aggregate).
__global__ __launch_bounds__(512)
void k_gemm2cm(const float* __restrict__ cpart, const float* __restrict__ mpart,
               const float* __restrict__ lpart, const float* __restrict__ Wo,
               float* __restrict__ op)
{
    __shared__ __align__(16) float alds[64*130];
    __shared__ float fac_s[128][8];
    __shared__ float inv_s[128];

    const int blk = blockIdx.x, t = threadIdx.x;
    const int jb = blk & 63;
    const int ks = blk >> 6;
    const int lane = t & 63;
    const int wvid = __builtin_amdgcn_readfirstlane(t >> 6);
    const int j0 = jb * 16 + wvid * 2;
    const int k0 = ks * 256;

    if (t < 128) {     // fac/inv table, bit-exact replica of k_merge math
        float mv[8], lv[8];
        #pragma unroll
        for (int i = 0; i < 8; ++i) { mv[i] = mpart[t*8 + i]; lv[i] = lpart[t*8 + i]; }
        float m = -INFINITY;
        #pragma unroll
        for (int i = 0; i < 8; ++i) m = fmaxf(m, mv[i]);
        float l = 0.f;
        float fc[8];
        #pragma unroll
        for (int i = 0; i < 8; ++i) { fc[i] = expf(mv[i] - m); l = fmaf(lv[i], fc[i], l); }
        inv_s[t] = 1.0f / l;
        #pragma unroll
        for (int i = 0; i < 8; ++i) fac_s[t][i] = fc[i];
    }

    double dac[2][2];
    dac[0][0] = 0.0; dac[0][1] = 0.0; dac[1][0] = 0.0; dac[1][1] = 0.0;

    const float* wbase = Wo + (size_t)j0 * (DIN + DSRC);   // c-half: cols 0..1023

    for (int kc = 0; kc < 256; kc += 64) {
        const int kg = k0 + kc;
        __syncthreads();       // orders fac_s/inv_s writes (first iter) + protects alds reuse
        #pragma unroll
        for (int q = 0; q < 4; ++q) {
            const int f4 = t + 512 * q;
            const int bb = f4 >> 4, c4 = f4 & 15;
            const float* cb = cpart + ((size_t)bb * 8) * DSRC + kg + c4 * 4;
            float4 s = make_float4(0.f, 0.f, 0.f, 0.f);
            #pragma unroll
            for (int i = 0; i < 8; ++i) {
                const float4 cp = *reinterpret_cast<const float4*>(cb + (size_t)i * DSRC);
                const float f = fac_s[bb][i];
                s.x = fmaf(cp.x, f, s.x);
                s.y = fmaf(cp.y, f, s.y);
                s.z = fmaf(cp.z, f, s.z);
                s.w = fmaf(cp.w, f, s.w);
            }
            const float iv = inv_s[bb];
            alds[(c4*4+0)*130 + bb] = s.x * iv;
            alds[(c4*4+1)*130 + bb] = s.y * iv;
            alds[(c4*4+2)*130 + bb] = s.z * iv;
            alds[(c4*4+3)*130 + bb] = s.w * iv;
        }
        __syncthreads();
        const float* wr = wbase + kg;
        #pragma unroll
        for (int kk16 = 0; kk16 < 64; kk16 += 16) {
            float fa[2][2];
            fa[0][0] = 0.f; fa[0][1] = 0.f; fa[1][0] = 0.f; fa[1][1] = 0.f;
            #pragma unroll
            for (int kk = 0; kk < 16; ++kk) {
                const int k = kk16 + kk;
                const float2 av = *reinterpret_cast<const float2*>(&alds[k*130 + 2*lane]);
                #pragma unroll
                for (int jj = 0; jj < 2; ++jj) {
                    const float wvv = wr[jj*(DIN+DSRC) + k];
                    fa[jj][0] = fmaf(wvv, av.x, fa[jj][0]);
                    fa[jj][1] = fmaf(wvv, av.y, fa[jj][1]);
                }
            }
            #pragma unroll
            for (int jj = 0; jj < 2; ++jj) {
                dac[jj][0] += (double)fa[jj][0];
                dac[jj][1] += (double)fa[jj][1];
            }
        }
    }
    #pragma unroll
    for (int i = 0; i < 2; ++i) {
        const int b = 2*lane + i;
        const size_t base = ((size_t)ks * BB + b) * DOUT + j0;
        op[base + 0] = (float)dac[0][i];
        op[base + 1] = (float)dac[1][i];
    }
}

// ---------------- L7: flat epilogue: out-reduce+tanh | a-output (R2-verified pattern) -------------
__global__ __launch_bounds__(512)
void k_epi(const float* __restrict__ op, const float* __restrict__ mpart,
           const float* __restrict__ lpart, const float* __restrict__ spart,
           const float* __restrict__ gtab, float* __restrict__ out)
{
    const int idx = blockIdx.x * 512 + threadIdx.x;
    if (idx < BB*DOUT) {
        float s = 0.f;
        #pragma unroll
        for (int ks = 0; ks < 8; ++ks) s += op[(size_t)ks * (BB*DOUT) + idx];
        out[idx] = tanhf(s);
    } else if (idx < BB*DOUT + BB*WLEN) {
        const int j = idx - BB*DOUT;
        const int b = j / WLEN, w = j - b*WLEN;
        float mv[8], lv[8];
        #pragma unroll
        for (int i = 0; i < 8; ++i) { mv[i] = mpart[b*8 + i]; lv[i] = lpart[b*8 + i]; }
        float m = -INFINITY;
        #pragma unroll
        for (int i = 0; i < 8; ++i) m = fmaxf(m, mv[i]);
        float l = 0.f;
        #pragma unroll
        for (int i = 0; i < 8; ++i) { const float f = expf(mv[i] - m); l = fmaf(lv[i], f, l); }
        const float inv = 1.0f / l;
        const int wc = w / WCH, i2 = w - wc*WCH;
        const float s = spart[(b*8 + wc)*WCH + i2];
        const float g = gtab[b*GW + w];
        out[DO_A + j] = expf(s - m) * inv * g;
    }
}

extern "C" void kernel_launch(void* const* d_in, const int* in_sizes, int n_in,
                              void* d_out, int out_size, void* d_ws, size_t ws_size,
                              hipStream_t stream)
{
    const float* input = (const float*)d_in[0];
    const float* src   = (const float*)d_in[1];
    const unsigned char* mask = (const unsigned char*)d_in[2];
    const float* Wi = (const float*)d_in[3];
    const float* Wo = (const float*)d_in[4];
    const float* W1 = (const float*)d_in[5];
    const float* b1 = (const float*)d_in[6];
    const float* W2 = (const float*)d_in[7];
    const float* b2 = (const float*)d_in[8];
    float* out = (float*)d_out;

    if (ws_size < (size_t)WS_NEED) return;

    char* ws = (char*)d_ws;
    int*    wsi     = (int*)   (ws + OFF_WSI);
    float*  pbuf    = (float*) (ws + OFF_P);
    int*    lengths = (int*)   (ws + OFF_LEN);
    float*  gtab    = (float*) (ws + OFF_GTAB);
    double* xp      = (double*)(ws + OFF_XP);
    float*  x32     = (float*) (ws + OFF_X32);
    double* z1p     = (double*)(ws + OFF_Z1P);
    float*  cpart   = (float*) (ws + OFF_CPART);
    float*  mpart   = (float*) (ws + OFF_MPART);
    float*  lpart   = (float*) (ws + OFF_LPART);
    float*  spart   = (float*) (ws + OFF_SPART);
    float*  op      = (float*) (ws + OFF_OP);

    // L1: gemm1 || gemm2-input-half || lengths  (all mutually independent)
    k_combo<<<640, 512, 0, stream>>>(input, Wi, Wo, mask, xp, op + 4*(size_t)BB*DOUT, lengths);
    // L2: x32 = f64-reduce(xp)
    k_xred<<<256, 512, 0, stream>>>(xp, x32);
    // L3: z1 partials = x32 @ W1^T
    k_fc1<<<128, 512, 0, stream>>>(x32, W1, z1p);
    // L4: fc2 -> W0/p/gtab/ws/we
    k_fc2<<<128, 64, 0, stream>>>(z1p, b1, W2, b2, lengths, wsi, pbuf, gtab, out);
    // L5: scores + local softmax + partial c
    k_score<<<dim3(8,128), 256, 0, stream>>>(x32, src, wsi, pbuf, lengths, gtab,
                                             cpart, mpart, lpart, spart);
    // L6: op[0..3] = merged-c @ Wo_c^T  (merge folded into staging)
    k_gemm2cm<<<256, 512, 0, stream>>>(cpart, mpart, lpart, Wo, op);
    // L7: out = tanh(sum op) | a
    k_epi<<<289, 512, 0, stream>>>(op, mpart, lpart, spart, gtab, out);
}